// Round 10
// baseline (513.723 us; speedup 1.0000x reference)
//
#include <hip/hip_runtime.h>
#include <hip/hip_bf16.h>

typedef __bf16 bf16x8 __attribute__((ext_vector_type(8)));
typedef float  f32x4  __attribute__((ext_vector_type(4)));
typedef unsigned short u16x8 __attribute__((ext_vector_type(8)));

#define HID 128
#define OUT 64
#define BN_EPS 1e-5f

__device__ __forceinline__ float bf2f(unsigned short u) {
  union { unsigned int i; float f; } c; c.i = ((unsigned)u) << 16; return c.f;
}

// ---------------- prep: xbf = bf16(x) AND histogram of dst ----------------
__global__ __launch_bounds__(256) void prep_k(
    const float* __restrict__ x, unsigned short* __restrict__ xbf,
    const int* __restrict__ dst, int* __restrict__ cnt, int n, int e)
{
  int gid = blockIdx.x * blockDim.x + threadIdx.x;
  int stride = gridDim.x * blockDim.x;
  int total = n * 32;               // f32x4 granules
  for (int idx = gid; idx < total; idx += stride) {
    f32x4 v = ((const f32x4*)x)[idx];
    ushort4 o;
    __bf16 b0 = (__bf16)v[0], b1 = (__bf16)v[1], b2 = (__bf16)v[2], b3 = (__bf16)v[3];
    o.x = *(unsigned short*)&b0; o.y = *(unsigned short*)&b1;
    o.z = *(unsigned short*)&b2; o.w = *(unsigned short*)&b3;
    ((ushort4*)xbf)[idx] = o;
  }
  for (int i = gid; i < e; i += stride)
    atomicAdd(&cnt[dst[i]], 1);
}

// ---------------- single-block exclusive scan (1024 thr); zero stats ----------------
__global__ __launch_bounds__(1024) void scan_k(
    const int* __restrict__ cnt, int* __restrict__ offsets,
    int* __restrict__ cursor, float* __restrict__ stats, int n)
{
  int t = threadIdx.x;
  if (t < 128) stats[t] = 0.f;
  __shared__ int part[1024];
  int chunk = (n + 1023) / 1024;
  int base = t * chunk;
  int s = 0;
  for (int i = 0; i < chunk; ++i) {
    int idx = base + i;
    if (idx < n) s += cnt[idx];
  }
  part[t] = s;
  __syncthreads();
  for (int off = 1; off < 1024; off <<= 1) {
    int v = 0;
    if (t >= off) v = part[t - off];
    __syncthreads();
    if (t >= off) part[t] += v;
    __syncthreads();
  }
  int run = (t == 0) ? 0 : part[t - 1];
  for (int i = 0; i < chunk; ++i) {
    int idx = base + i;
    if (idx < n) {
      offsets[idx] = run;
      cursor[idx]  = run;
      run += cnt[idx];
    }
  }
  if (t == 1023) offsets[n] = run;
}

// ---------------- place src ids (ushort) into dst-sorted order ----------------
__global__ __launch_bounds__(256) void place_k(
    const int* __restrict__ src, const int* __restrict__ dst,
    int* __restrict__ cursor, unsigned short* __restrict__ sorted_src, int e)
{
  int stride = gridDim.x * blockDim.x;
  for (int i = blockIdx.x * blockDim.x + threadIdx.x; i < e; i += stride) {
    int pos = atomicAdd(&cursor[dst[i]], 1);
    sorted_src[pos] = (unsigned short)src[i];
  }
}

// ---- fused: 8 waves gather 8 nodes IN PARALLEL (one wave per node) into LDS,
//      then y2 = bf16(relu(agg@w1^T+b1)@w2^T). No HBM round trip for agg. ----
__global__ __launch_bounds__(512, 8) void aggmlp_k(
    const unsigned short* __restrict__ xbf, const unsigned short* __restrict__ sorted_src,
    const int* __restrict__ offsets,
    const float* __restrict__ w1, const float* __restrict__ b1,
    const float* __restrict__ w2, unsigned short* __restrict__ y2, int n)
{
  __shared__ float aggs[8][132];
  __shared__ float h2s[8][132];
  int t = threadIdx.x;
  int rbase = blockIdx.x * 8;
  int wv = t >> 6, lane = t & 63;
  int qtr = lane >> 4, l16 = lane & 15;

  // gather: wave wv -> node rbase+wv, all 8 waves concurrent, 8 edges in flight
  {
    int node = rbase + wv;
    int beg = offsets[node], end = offsets[node + 1];
    float a0[8] = {}, a1[8] = {};
    int i = beg + qtr;
    for (; i + 4 < end; i += 8) {
      int s0 = sorted_src[i];
      int s1 = sorted_src[i + 4];
      u16x8 v0 = *(const u16x8*)(xbf + (size_t)s0 * HID + l16 * 8);
      u16x8 v1 = *(const u16x8*)(xbf + (size_t)s1 * HID + l16 * 8);
      #pragma unroll
      for (int j = 0; j < 8; ++j) { a0[j] += bf2f(v0[j]); a1[j] += bf2f(v1[j]); }
    }
    if (i < end) {
      int s0 = sorted_src[i];
      u16x8 v0 = *(const u16x8*)(xbf + (size_t)s0 * HID + l16 * 8);
      #pragma unroll
      for (int j = 0; j < 8; ++j) a0[j] += bf2f(v0[j]);
    }
    #pragma unroll
    for (int j = 0; j < 8; ++j) a0[j] += a1[j];
    #pragma unroll
    for (int j = 0; j < 8; ++j) a0[j] += __shfl_xor(a0[j], 16, 64);
    #pragma unroll
    for (int j = 0; j < 8; ++j) a0[j] += __shfl_xor(a0[j], 32, 64);
    if (qtr == 0) {
      f32x4 lo = {a0[0], a0[1], a0[2], a0[3]};
      f32x4 hi = {a0[4], a0[5], a0[6], a0[7]};
      *(f32x4*)&aggs[wv][l16 * 8]     = lo;
      *(f32x4*)&aggs[wv][l16 * 8 + 4] = hi;
    }
  }
  __syncthreads();

  // phase A: h2a = relu(agg @ w1^T + b1); 512 thr = 128 j x 4 rh; 2 rows each
  {
    int j = t & 127, rh = t >> 7;
    const f32x4* w1r = (const f32x4*)(w1 + (size_t)j * HID);
    float bj = b1[j];
    float acc0 = bj, acc1 = bj;
    for (int k = 0; k < 32; ++k) {
      f32x4 w = w1r[k];
      f32x4 aA = ((const f32x4*)&aggs[rh * 2][0])[k];      // broadcast
      f32x4 aB = ((const f32x4*)&aggs[rh * 2 + 1][0])[k];  // broadcast
      acc0 += w[0] * aA[0] + w[1] * aA[1] + w[2] * aA[2] + w[3] * aA[3];
      acc1 += w[0] * aB[0] + w[1] * aB[1] + w[2] * aB[2] + w[3] * aB[3];
    }
    h2s[rh * 2][j]     = fmaxf(acc0, 0.f);
    h2s[rh * 2 + 1][j] = fmaxf(acc1, 0.f);
  }
  __syncthreads();

  // phase B: y2 = bf16(h2a @ w2^T); 512 thr = 64 o x 8 rq; 1 row each
  {
    int o = t & 63, rq = t >> 6;
    const f32x4* w2r = (const f32x4*)(w2 + (size_t)o * HID);
    float acc = 0.f;
    for (int k = 0; k < 32; ++k) {
      f32x4 w = w2r[k];
      f32x4 a = ((const f32x4*)&h2s[rq][0])[k];            // broadcast
      acc += w[0] * a[0] + w[1] * a[1] + w[2] * a[2] + w[3] * a[3];
    }
    __bf16 b = (__bf16)acc;
    y2[(size_t)(rbase + rq) * OUT + o] = *(unsigned short*)&b;
  }
}

// ---- fused: 8 waves gather y2 segments in parallel into LDS;
//      h = (1-eps)*(x@fc_w^T+fc_b) + eps*(aggy+b2); hbf; BN stats ----
__global__ __launch_bounds__(512, 8) void aggcomb_k(
    const float* __restrict__ x, const unsigned short* __restrict__ y2,
    const unsigned short* __restrict__ sorted_src, const int* __restrict__ offsets,
    const float* __restrict__ fcw, const float* __restrict__ fcb,
    const float* __restrict__ b2, const float* __restrict__ eps,
    float* __restrict__ h, unsigned short* __restrict__ hbf,
    float* __restrict__ stats, int n)
{
  __shared__ float xs[8][132];
  __shared__ float ay[8][68];
  __shared__ float ls[512], lss[512];
  int t = threadIdx.x;
  int rbase = blockIdx.x * 8;
  int wv = t >> 6, lane = t & 63;
  int qtr = lane >> 4, l16 = lane & 15;

  // stage x tile (8 rows x 32 f32x4)
  for (int idx = t; idx < 8 * 32; idx += 512) {
    int r = idx >> 5, c = idx & 31;
    ((f32x4*)&xs[r][0])[c] = ((const f32x4*)(x + (size_t)(rbase + r) * HID))[c];
  }

  // gather: wave wv -> node rbase+wv, concurrent
  {
    int node = rbase + wv;
    int beg = offsets[node], end = offsets[node + 1];
    f32x4 a0 = {0.f, 0.f, 0.f, 0.f}, a1 = {0.f, 0.f, 0.f, 0.f};
    int i = beg + qtr;
    for (; i + 4 < end; i += 8) {
      int s0 = sorted_src[i];
      int s1 = sorted_src[i + 4];
      ushort4 v0 = *(const ushort4*)(y2 + (size_t)s0 * OUT + l16 * 4);
      ushort4 v1 = *(const ushort4*)(y2 + (size_t)s1 * OUT + l16 * 4);
      a0[0] += bf2f(v0.x); a0[1] += bf2f(v0.y); a0[2] += bf2f(v0.z); a0[3] += bf2f(v0.w);
      a1[0] += bf2f(v1.x); a1[1] += bf2f(v1.y); a1[2] += bf2f(v1.z); a1[3] += bf2f(v1.w);
    }
    if (i < end) {
      int s0 = sorted_src[i];
      ushort4 v0 = *(const ushort4*)(y2 + (size_t)s0 * OUT + l16 * 4);
      a0[0] += bf2f(v0.x); a0[1] += bf2f(v0.y); a0[2] += bf2f(v0.z); a0[3] += bf2f(v0.w);
    }
    a0 += a1;
    f32x4 other;
    #pragma unroll
    for (int j = 0; j < 4; ++j) other[j] = __shfl_xor(a0[j], 16, 64);
    a0 += other;
    #pragma unroll
    for (int j = 0; j < 4; ++j) other[j] = __shfl_xor(a0[j], 32, 64);
    a0 += other;
    if (qtr == 0)
      *(f32x4*)&ay[wv][l16 * 4] = a0;
  }
  __syncthreads();

  // main: 512 thr = 64 o x 8 rq; 1 row each
  int o = t & 63, rq = t >> 6;
  const f32x4* fwr = (const f32x4*)(fcw + (size_t)o * HID);
  float a1v = fcb[o];
  for (int k = 0; k < 32; ++k) {
    f32x4 w = fwr[k];
    f32x4 a = ((const f32x4*)&xs[rq][0])[k];               // broadcast
    a1v += w[0] * a[0] + w[1] * a[1] + w[2] * a[2] + w[3] * a[3];
  }
  int row = rbase + rq;
  float a2 = ay[rq][o] + b2[o];
  float ev = eps[row];
  float hv = (1.f - ev) * a1v + ev * a2;
  h[(size_t)row * OUT + o] = hv;
  __bf16 hb = (__bf16)hv;
  hbf[(size_t)row * OUT + o] = *(unsigned short*)&hb;
  ls[t] = hv; lss[t] = hv * hv;
  __syncthreads();
  if (t < 64) {
    float s = 0.f, ss = 0.f;
    #pragma unroll
    for (int i = 0; i < 8; ++i) { s += ls[t + 64 * i]; ss += lss[t + 64 * i]; }
    atomicAdd(&stats[t], s);
    atomicAdd(&stats[64 + t], ss);
  }
}

// ---------------- hn = (h - mean) * rsqrt(var+eps) * gamma + beta ----------------
__global__ __launch_bounds__(256) void hn_k(
    const float* __restrict__ h, const float* __restrict__ stats,
    const float* __restrict__ gamma, const float* __restrict__ beta,
    float* __restrict__ outp, int n)
{
  int stride = gridDim.x * blockDim.x;
  int total  = n * OUT;
  float inv_n = 1.f / (float)n;
  for (int idx = blockIdx.x * blockDim.x + threadIdx.x; idx < total; idx += stride) {
    int col = idx & 63;
    float mean = stats[col] * inv_n;
    float var  = stats[64 + col] * inv_n - mean * mean;
    float sc   = rsqrtf(var + BN_EPS) * gamma[col];
    outp[idx] = (h[idx] - mean) * sc + beta[col];
  }
}

// ---- ret = 0.5 * [hbf|xbf] @ [hbf|xbf]^T, symmetric (bi<=bj); LDS aliased ----
__global__ __launch_bounds__(256, 3) void gemm_k(
    const unsigned short* __restrict__ hbf, const unsigned short* __restrict__ xbf,
    float* __restrict__ out, int n, int nwg)
{
  __shared__ char pool[64 * 132 * 4];          // 33.8 KB
  __bf16* As = (__bf16*)pool;
  __bf16* Bs = (__bf16*)(pool + 16384);
  float*  T  = (float*)pool;

  int nb = n >> 7;                  // 125
  int orig = blockIdx.x;
  int q = nwg >> 3, r = nwg & 7;
  int xcd = orig & 7, idx8 = orig >> 3;
  int bid = (xcd < r ? xcd * (q + 1) : r * (q + 1) + (xcd - r) * q) + idx8;

  int bi = 0, rem = bid;
  while (rem >= nb - bi) { rem -= nb - bi; ++bi; }
  int bj = bi + rem;
  int t = threadIdx.x;
  int w = t >> 6, lane = t & 63;
  int wr = (w >> 1) << 6;
  int wc = (w & 1) << 6;
  int lr = lane & 15, lg = lane >> 4;

  const uint4* ha = (const uint4*)(hbf + (size_t)bi * 128 * OUT);
  const uint4* hb = (const uint4*)(hbf + (size_t)bj * 128 * OUT);
  const uint4* xa = (const uint4*)(xbf + (size_t)bi * 128 * HID);
  const uint4* xb = (const uint4*)(xbf + (size_t)bj * 128 * HID);
  uint4* Asv = (uint4*)As;
  uint4* Bsv = (uint4*)Bs;

  f32x4 acc[4][4] = {};
  #pragma unroll
  for (int kc = 0; kc < 3; ++kc) {  // K = 192: kc0 <- hbf, kc1/2 <- xbf
    #pragma unroll
    for (int it = 0; it < 4; ++it) {
      int ch = t + it * 256;
      int row = ch >> 3, c = ch & 7;
      int sw = row * 8 + (c ^ (row & 7));
      uint4 va, vb;
      if (kc == 0) { va = ha[row * 8 + c];                  vb = hb[row * 8 + c]; }
      else         { va = xa[row * 16 + (kc - 1) * 8 + c];  vb = xb[row * 16 + (kc - 1) * 8 + c]; }
      Asv[sw] = va;
      Bsv[sw] = vb;
    }
    __syncthreads();
    const bf16x8* Ac = (const bf16x8*)As;
    const bf16x8* Bc = (const bf16x8*)Bs;
    #pragma unroll
    for (int ks = 0; ks < 2; ++ks) {
      bf16x8 a[4], b[4];
      #pragma unroll
      for (int m = 0; m < 4; ++m) {
        int ar = wr + m * 16 + lr;
        int br = wc + m * 16 + lr;
        a[m] = Ac[ar * 8 + ((ks * 4 + lg) ^ (ar & 7))];
        b[m] = Bc[br * 8 + ((ks * 4 + lg) ^ (br & 7))];
      }
      #pragma unroll
      for (int m = 0; m < 4; ++m)
        #pragma unroll
        for (int nn = 0; nn < 4; ++nn)
          acc[m][nn] = __builtin_amdgcn_mfma_f32_16x16x32_bf16(a[m], b[nn], acc[m][nn], 0, 0, 0);
    }
    __syncthreads();
  }

  #pragma unroll
  for (int m = 0; m < 4; ++m)
    #pragma unroll
    for (int nn = 0; nn < 4; ++nn)
      acc[m][nn] = acc[m][nn] * 0.5f;

  size_t N = (size_t)n;

  if (bi != bj) {
    #pragma unroll
    for (int p = 0; p < 2; ++p) {
      if ((wc >> 6) == p) {
        #pragma unroll
        for (int m = 0; m < 4; ++m)
          #pragma unroll
          for (int nn = 0; nn < 4; ++nn) {
            int c  = nn * 16 + lr;
            int r0 = wr + m * 16 + lg * 4;
            *(f32x4*)&T[c * 132 + r0] = acc[m][nn];
          }
      }
      __syncthreads();
      #pragma unroll
      for (int it = 0; it < 8; ++it) {
        int idx = t + it * 256;
        int rr = idx >> 5, c4 = idx & 31;
        f32x4 v = *(const f32x4*)&T[rr * 132 + c4 * 4];
        *(f32x4*)&out[(size_t)(bj * 128 + p * 64 + rr) * N + bi * 128 + c4 * 4] = v;
      }
      __syncthreads();
    }
  }

  #pragma unroll
  for (int m = 0; m < 4; ++m) {
    size_t gr0 = (size_t)(bi * 128 + wr + m * 16 + lg * 4);
    #pragma unroll
    for (int nn = 0; nn < 4; ++nn) {
      int gc = bj * 128 + wc + nn * 16 + lr;
      #pragma unroll
      for (int r = 0; r < 4; ++r)
        out[(gr0 + r) * N + gc] = acc[m][nn][r];
    }
  }
}

extern "C" void kernel_launch(void* const* d_in, const int* in_sizes, int n_in,
                              void* d_out, int out_size, void* d_ws, size_t ws_size,
                              hipStream_t stream) {
  const float* x    = (const float*)d_in[0];
  const int*   src  = (const int*)d_in[1];
  const int*   dst  = (const int*)d_in[2];
  const float* fcw  = (const float*)d_in[3];
  const float* fcb  = (const float*)d_in[4];
  const float* w1   = (const float*)d_in[5];
  const float* b1   = (const float*)d_in[6];
  const float* w2   = (const float*)d_in[7];
  const float* b2   = (const float*)d_in[8];
  const float* eps  = (const float*)d_in[9];
  const float* gamma= (const float*)d_in[10];
  const float* beta = (const float*)d_in[11];
  int n = in_sizes[0] / HID;   // 16000
  int e = in_sizes[1];         // 512000
  float* out = (float*)d_out;

  char* ws = (char*)d_ws;
  size_t off = 0;
  float* h     = (float*)(ws + off); off += (size_t)n * OUT * 4;                  // 4 MB
  unsigned short* xbf = (unsigned short*)(ws + off); off += (size_t)n * HID * 2;  // 4 MB
  unsigned short* hbf = (unsigned short*)(ws + off); off += (size_t)n * OUT * 2;  // 2 MB
  unsigned short* y2  = (unsigned short*)(ws + off); off += (size_t)n * OUT * 2;  // 2 MB
  float* stats = (float*)(ws + off); off += 512;
  int* cnt     = (int*)(ws + off); off += (size_t)n * 4;
  int* offsets = (int*)(ws + off); off += (size_t)(n + 1) * 4;
  int* cursor  = (int*)(ws + off); off += (size_t)n * 4;
  unsigned short* sorted_src = (unsigned short*)(ws + off); off += (size_t)e * 2;

  hipMemsetAsync(cnt, 0, (size_t)n * 4, stream);

  // xbf = bf16(x); cnt = histogram(dst)
  prep_k<<<2048, 256, 0, stream>>>(x, xbf, dst, cnt, n, e);
  // exclusive scan; zero stats
  scan_k<<<1, 1024, 0, stream>>>(cnt, offsets, cursor, stats, n);
  // sorted_src (ushort)
  place_k<<<512, 256, 0, stream>>>(src, dst, cursor, sorted_src, e);

  // fused gather(A@x) -> MLP -> y2   (one wave per node; agg never leaves LDS)
  aggmlp_k<<<n / 8, 512, 0, stream>>>(xbf, sorted_src, offsets, w1, b1, w2, y2, n);
  // fused gather(A@y2) -> combine -> h, hbf, BN stats
  aggcomb_k<<<n / 8, 512, 0, stream>>>(x, y2, sorted_src, offsets, fcw, fcb, b2, eps,
                                       h, hbf, stats, n);
  hn_k<<<1024, 256, 0, stream>>>(h, stats, gamma, beta, out + (size_t)n * n, n);

  int nb = n >> 7;
  int nwg = nb * (nb + 1) / 2;
  gemm_k<<<nwg, 256, 0, stream>>>(hbf, xbf, out, n, nwg);
}

// Round 11
// 394.277 us; speedup vs baseline: 1.3029x; 1.3029x over previous
//
#include <hip/hip_runtime.h>
#include <hip/hip_bf16.h>

typedef __bf16 bf16x8 __attribute__((ext_vector_type(8)));
typedef float  f32x4  __attribute__((ext_vector_type(4)));
typedef unsigned short u16x8 __attribute__((ext_vector_type(8)));

#define HID 128
#define OUT 64
#define BN_EPS 1e-5f

__device__ __forceinline__ float bf2f(unsigned short u) {
  union { unsigned int i; float f; } c; c.i = ((unsigned)u) << 16; return c.f;
}

// ---------------- prep: xbf = bf16(x) AND histogram of dst ----------------
__global__ __launch_bounds__(256) void prep_k(
    const float* __restrict__ x, unsigned short* __restrict__ xbf,
    const int* __restrict__ dst, int* __restrict__ cnt, int n, int e)
{
  int gid = blockIdx.x * blockDim.x + threadIdx.x;
  int stride = gridDim.x * blockDim.x;
  int total = n * 32;               // f32x4 granules
  for (int idx = gid; idx < total; idx += stride) {
    f32x4 v = ((const f32x4*)x)[idx];
    ushort4 o;
    __bf16 b0 = (__bf16)v[0], b1 = (__bf16)v[1], b2 = (__bf16)v[2], b3 = (__bf16)v[3];
    o.x = *(unsigned short*)&b0; o.y = *(unsigned short*)&b1;
    o.z = *(unsigned short*)&b2; o.w = *(unsigned short*)&b3;
    ((ushort4*)xbf)[idx] = o;
  }
  for (int i = gid; i < e; i += stride)
    atomicAdd(&cnt[dst[i]], 1);
}

// ---------------- single-block exclusive scan (1024 thr); zero stats ----------------
__global__ __launch_bounds__(1024) void scan_k(
    const int* __restrict__ cnt, int* __restrict__ offsets,
    int* __restrict__ cursor, float* __restrict__ stats, int n)
{
  int t = threadIdx.x;
  if (t < 128) stats[t] = 0.f;
  __shared__ int part[1024];
  int chunk = (n + 1023) / 1024;
  int base = t * chunk;
  int s = 0;
  for (int i = 0; i < chunk; ++i) {
    int idx = base + i;
    if (idx < n) s += cnt[idx];
  }
  part[t] = s;
  __syncthreads();
  for (int off = 1; off < 1024; off <<= 1) {
    int v = 0;
    if (t >= off) v = part[t - off];
    __syncthreads();
    if (t >= off) part[t] += v;
    __syncthreads();
  }
  int run = (t == 0) ? 0 : part[t - 1];
  for (int i = 0; i < chunk; ++i) {
    int idx = base + i;
    if (idx < n) {
      offsets[idx] = run;
      cursor[idx]  = run;
      run += cnt[idx];
    }
  }
  if (t == 1023) offsets[n] = run;
}

// ---------------- place src ids (ushort) into dst-sorted order ----------------
__global__ __launch_bounds__(256) void place_k(
    const int* __restrict__ src, const int* __restrict__ dst,
    int* __restrict__ cursor, unsigned short* __restrict__ sorted_src, int e)
{
  int stride = gridDim.x * blockDim.x;
  for (int i = blockIdx.x * blockDim.x + threadIdx.x; i < e; i += stride) {
    int pos = atomicAdd(&cursor[dst[i]], 1);
    sorted_src[pos] = (unsigned short)src[i];
  }
}

// ---- agg[d] = segment sum of bf16 xbf (N x 128); one wave per d; 12 edges in flight ----
__global__ __launch_bounds__(256) void aggx_k(
    const unsigned short* __restrict__ xbf, const unsigned short* __restrict__ sorted_src,
    const int* __restrict__ offsets, float* __restrict__ agg, int n)
{
  int wave = (blockIdx.x * 256 + threadIdx.x) >> 6;
  int lane = threadIdx.x & 63;
  if (wave >= n) return;
  int qtr = lane >> 4;              // 4 quarter-waves: one edge each
  int l16 = lane & 15;              // 16 lanes x 8 bf16 = one 128-col row
  int beg = offsets[wave], end = offsets[wave + 1];
  float a0[8] = {}, a1[8] = {}, a2[8] = {};
  int i = beg + qtr;
  for (; i + 8 < end; i += 12) {
    int s0 = sorted_src[i];
    int s1 = sorted_src[i + 4];
    int s2 = sorted_src[i + 8];
    u16x8 v0 = *(const u16x8*)(xbf + (size_t)s0 * HID + l16 * 8);
    u16x8 v1 = *(const u16x8*)(xbf + (size_t)s1 * HID + l16 * 8);
    u16x8 v2 = *(const u16x8*)(xbf + (size_t)s2 * HID + l16 * 8);
    #pragma unroll
    for (int j = 0; j < 8; ++j) { a0[j] += bf2f(v0[j]); a1[j] += bf2f(v1[j]); a2[j] += bf2f(v2[j]); }
  }
  for (; i < end; i += 4) {
    int s0 = sorted_src[i];
    u16x8 v0 = *(const u16x8*)(xbf + (size_t)s0 * HID + l16 * 8);
    #pragma unroll
    for (int j = 0; j < 8; ++j) a0[j] += bf2f(v0[j]);
  }
  #pragma unroll
  for (int j = 0; j < 8; ++j) a0[j] += a1[j] + a2[j];
  #pragma unroll
  for (int j = 0; j < 8; ++j) a0[j] += __shfl_xor(a0[j], 16, 64);
  #pragma unroll
  for (int j = 0; j < 8; ++j) a0[j] += __shfl_xor(a0[j], 32, 64);
  if (qtr == 0) {
    f32x4 lo = {a0[0], a0[1], a0[2], a0[3]};
    f32x4 hi = {a0[4], a0[5], a0[6], a0[7]};
    *(f32x4*)(agg + (size_t)wave * HID + l16 * 8)     = lo;
    *(f32x4*)(agg + (size_t)wave * HID + l16 * 8 + 4) = hi;
  }
}

// ---- aggy[d] = segment sum of bf16 y2 (N x 64); one wave per d; 12 edges in flight ----
__global__ __launch_bounds__(256) void agg2y_k(
    const unsigned short* __restrict__ y2, const unsigned short* __restrict__ sorted_src,
    const int* __restrict__ offsets, float* __restrict__ aggy, int n)
{
  int wave = (blockIdx.x * 256 + threadIdx.x) >> 6;
  int lane = threadIdx.x & 63;
  if (wave >= n) return;
  int qtr = lane >> 4;
  int l16 = lane & 15;
  int beg = offsets[wave], end = offsets[wave + 1];
  f32x4 a0 = {0.f, 0.f, 0.f, 0.f}, a1 = {0.f, 0.f, 0.f, 0.f}, a2 = {0.f, 0.f, 0.f, 0.f};
  int i = beg + qtr;
  for (; i + 8 < end; i += 12) {
    int s0 = sorted_src[i];
    int s1 = sorted_src[i + 4];
    int s2 = sorted_src[i + 8];
    ushort4 v0 = *(const ushort4*)(y2 + (size_t)s0 * OUT + l16 * 4);
    ushort4 v1 = *(const ushort4*)(y2 + (size_t)s1 * OUT + l16 * 4);
    ushort4 v2 = *(const ushort4*)(y2 + (size_t)s2 * OUT + l16 * 4);
    a0[0] += bf2f(v0.x); a0[1] += bf2f(v0.y); a0[2] += bf2f(v0.z); a0[3] += bf2f(v0.w);
    a1[0] += bf2f(v1.x); a1[1] += bf2f(v1.y); a1[2] += bf2f(v1.z); a1[3] += bf2f(v1.w);
    a2[0] += bf2f(v2.x); a2[1] += bf2f(v2.y); a2[2] += bf2f(v2.z); a2[3] += bf2f(v2.w);
  }
  for (; i < end; i += 4) {
    int s0 = sorted_src[i];
    ushort4 v0 = *(const ushort4*)(y2 + (size_t)s0 * OUT + l16 * 4);
    a0[0] += bf2f(v0.x); a0[1] += bf2f(v0.y); a0[2] += bf2f(v0.z); a0[3] += bf2f(v0.w);
  }
  a0 += a1; a0 += a2;
  f32x4 other;
  #pragma unroll
  for (int j = 0; j < 4; ++j) other[j] = __shfl_xor(a0[j], 16, 64);
  a0 += other;
  #pragma unroll
  for (int j = 0; j < 4; ++j) other[j] = __shfl_xor(a0[j], 32, 64);
  a0 += other;
  if (qtr == 0)
    *(f32x4*)(aggy + (size_t)wave * OUT + l16 * 4) = a0;
}

// ---- y2 = bf16(relu(agg @ w1^T + b1) @ w2^T); h2a lives only in LDS ----
__global__ __launch_bounds__(256) void mlp_fused_k(
    const float* __restrict__ agg, const float* __restrict__ w1,
    const float* __restrict__ b1, const float* __restrict__ w2,
    unsigned short* __restrict__ y2, int n)
{
  __shared__ float aggs[16][132];
  __shared__ float h2s[16][132];
  int t = threadIdx.x;
  int rbase = blockIdx.x * 16;

  for (int idx = t; idx < 16 * 32; idx += 256) {
    int r = idx >> 5, c = idx & 31;
    ((f32x4*)&aggs[r][0])[c] = ((const f32x4*)(agg + (size_t)(rbase + r) * HID))[c];
  }
  __syncthreads();

  {
    int j = t & 127, rh = t >> 7;
    const f32x4* w1r = (const f32x4*)(w1 + (size_t)j * HID);
    float acc[8];
    float bj = b1[j];
    #pragma unroll
    for (int p = 0; p < 8; ++p) acc[p] = bj;
    for (int k = 0; k < 32; ++k) {
      f32x4 w = w1r[k];
      #pragma unroll
      for (int p = 0; p < 8; ++p) {
        f32x4 a = ((const f32x4*)&aggs[rh * 8 + p][0])[k];
        acc[p] += w[0] * a[0] + w[1] * a[1] + w[2] * a[2] + w[3] * a[3];
      }
    }
    #pragma unroll
    for (int p = 0; p < 8; ++p) h2s[rh * 8 + p][j] = fmaxf(acc[p], 0.f);
  }
  __syncthreads();

  {
    int o = t & 63, rq = t >> 6;
    const f32x4* w2r = (const f32x4*)(w2 + (size_t)o * HID);
    float acc[4] = {0.f, 0.f, 0.f, 0.f};
    for (int k = 0; k < 32; ++k) {
      f32x4 w = w2r[k];
      #pragma unroll
      for (int p = 0; p < 4; ++p) {
        f32x4 a = ((const f32x4*)&h2s[rq + p * 4][0])[k];
        acc[p] += w[0] * a[0] + w[1] * a[1] + w[2] * a[2] + w[3] * a[3];
      }
    }
    #pragma unroll
    for (int p = 0; p < 4; ++p) {
      __bf16 b = (__bf16)acc[p];
      y2[(size_t)(rbase + rq + p * 4) * OUT + o] = *(unsigned short*)&b;
    }
  }
}

// ---- h = (1-eps)*(x@fc_w^T+fc_b) + eps*(aggy + b2); hbf = bf16(h); BN stats ----
__global__ __launch_bounds__(256) void combine_k(
    const float* __restrict__ x, const float* __restrict__ aggy,
    const float* __restrict__ fcw, const float* __restrict__ fcb,
    const float* __restrict__ b2,
    const float* __restrict__ eps, float* __restrict__ h,
    unsigned short* __restrict__ hbf, float* __restrict__ stats, int n)
{
  __shared__ float xs[32][132];
  __shared__ float ls[256], lss[256];
  int t = threadIdx.x;
  int rbase = blockIdx.x * 32;

  for (int idx = t; idx < 32 * 32; idx += 256) {
    int r = idx >> 5, c = idx & 31;
    ((f32x4*)&xs[r][0])[c] = ((const f32x4*)(x + (size_t)(rbase + r) * HID))[c];
  }
  __syncthreads();

  int o = t & 63, rq = t >> 6;
  const f32x4* fwr = (const f32x4*)(fcw + (size_t)o * HID);
  float fb = fcb[o], bb = b2[o];
  float acc[8];
  #pragma unroll
  for (int p = 0; p < 8; ++p) acc[p] = fb;
  for (int k = 0; k < 32; ++k) {
    f32x4 w = fwr[k];
    #pragma unroll
    for (int p = 0; p < 8; ++p) {
      f32x4 a = ((const f32x4*)&xs[rq + p * 4][0])[k];
      acc[p] += w[0] * a[0] + w[1] * a[1] + w[2] * a[2] + w[3] * a[3];
    }
  }
  float s = 0.f, ss = 0.f;
  #pragma unroll
  for (int p = 0; p < 8; ++p) {
    int row = rbase + rq + p * 4;
    float a2 = aggy[(size_t)row * OUT + o] + bb;
    float ev = eps[row];
    float hv = (1.f - ev) * acc[p] + ev * a2;
    h[(size_t)row * OUT + o] = hv;
    __bf16 hb = (__bf16)hv;
    hbf[(size_t)row * OUT + o] = *(unsigned short*)&hb;
    s += hv; ss += hv * hv;
  }
  ls[t] = s; lss[t] = ss;
  __syncthreads();
  if (t < 64) {
    s  = ls[t]  + ls[t + 64]  + ls[t + 128]  + ls[t + 192];
    ss = lss[t] + lss[t + 64] + lss[t + 128] + lss[t + 192];
    atomicAdd(&stats[t], s);
    atomicAdd(&stats[64 + t], ss);
  }
}

// ---------------- hn = (h - mean) * rsqrt(var+eps) * gamma + beta ----------------
__global__ __launch_bounds__(256) void hn_k(
    const float* __restrict__ h, const float* __restrict__ stats,
    const float* __restrict__ gamma, const float* __restrict__ beta,
    float* __restrict__ outp, int n)
{
  int stride = gridDim.x * blockDim.x;
  int total  = n * OUT;
  float inv_n = 1.f / (float)n;
  for (int idx = blockIdx.x * blockDim.x + threadIdx.x; idx < total; idx += stride) {
    int col = idx & 63;
    float mean = stats[col] * inv_n;
    float var  = stats[64 + col] * inv_n - mean * mean;
    float sc   = rsqrtf(var + BN_EPS) * gamma[col];
    outp[idx] = (h[idx] - mean) * sc + beta[col];
  }
}

// ---- ret = 0.5 * [hbf|xbf] @ [hbf|xbf]^T, symmetric (bi<=bj);
//      32 KB LDS pool (As+Bs aliased with 32-col transpose T) -> 4 blocks/CU ----
__global__ __launch_bounds__(256, 4) void gemm_k(
    const unsigned short* __restrict__ hbf, const unsigned short* __restrict__ xbf,
    float* __restrict__ out, int n, int nwg)
{
  __shared__ char pool[32768];                 // exactly 32 KB
  __bf16* As = (__bf16*)pool;                  // 16 KB
  __bf16* Bs = (__bf16*)(pool + 16384);        // 16 KB
  float*  T  = (float*)pool;                   // 32x132 f32 = 16.9 KB (aliased)

  int nb = n >> 7;                  // 125
  int orig = blockIdx.x;
  int q = nwg >> 3, r = nwg & 7;
  int xcd = orig & 7, idx8 = orig >> 3;
  int bid = (xcd < r ? xcd * (q + 1) : r * (q + 1) + (xcd - r) * q) + idx8;

  int bi = 0, rem = bid;
  while (rem >= nb - bi) { rem -= nb - bi; ++bi; }
  int bj = bi + rem;
  int t = threadIdx.x;
  int w = t >> 6, lane = t & 63;
  int wr = (w >> 1) << 6;
  int wc = (w & 1) << 6;
  int lr = lane & 15, lg = lane >> 4;

  const uint4* ha = (const uint4*)(hbf + (size_t)bi * 128 * OUT);
  const uint4* hb = (const uint4*)(hbf + (size_t)bj * 128 * OUT);
  const uint4* xa = (const uint4*)(xbf + (size_t)bi * 128 * HID);
  const uint4* xb = (const uint4*)(xbf + (size_t)bj * 128 * HID);
  uint4* Asv = (uint4*)As;
  uint4* Bsv = (uint4*)Bs;

  f32x4 acc[4][4] = {};
  #pragma unroll
  for (int kc = 0; kc < 3; ++kc) {  // K = 192: kc0 <- hbf, kc1/2 <- xbf
    #pragma unroll
    for (int it = 0; it < 4; ++it) {
      int ch = t + it * 256;
      int row = ch >> 3, c = ch & 7;
      int sw = row * 8 + (c ^ (row & 7));
      uint4 va, vb;
      if (kc == 0) { va = ha[row * 8 + c];                  vb = hb[row * 8 + c]; }
      else         { va = xa[row * 16 + (kc - 1) * 8 + c];  vb = xb[row * 16 + (kc - 1) * 8 + c]; }
      Asv[sw] = va;
      Bsv[sw] = vb;
    }
    __syncthreads();
    const bf16x8* Ac = (const bf16x8*)As;
    const bf16x8* Bc = (const bf16x8*)Bs;
    #pragma unroll
    for (int ks = 0; ks < 2; ++ks) {
      bf16x8 a[4], b[4];
      #pragma unroll
      for (int m = 0; m < 4; ++m) {
        int ar = wr + m * 16 + lr;
        int br = wc + m * 16 + lr;
        a[m] = Ac[ar * 8 + ((ks * 4 + lg) ^ (ar & 7))];
        b[m] = Bc[br * 8 + ((ks * 4 + lg) ^ (br & 7))];
      }
      #pragma unroll
      for (int m = 0; m < 4; ++m)
        #pragma unroll
        for (int nn = 0; nn < 4; ++nn)
          acc[m][nn] = __builtin_amdgcn_mfma_f32_16x16x32_bf16(a[m], b[nn], acc[m][nn], 0, 0, 0);
    }
    __syncthreads();
  }

  #pragma unroll
  for (int m = 0; m < 4; ++m)
    #pragma unroll
    for (int nn = 0; nn < 4; ++nn)
      acc[m][nn] = acc[m][nn] * 0.5f;

  size_t N = (size_t)n;

  // mirrored tile (bj,bi): 4 passes of 32 columns through the 16.9 KB T
  if (bi != bj) {
    #pragma unroll
    for (int p = 0; p < 4; ++p) {
      if ((wc >> 6) == (p >> 1)) {
        int nn0 = (p & 1) * 2;
        #pragma unroll
        for (int m = 0; m < 4; ++m)
          #pragma unroll
          for (int nn = nn0; nn < nn0 + 2; ++nn) {
            int c  = nn * 16 + lr - (p & 1) * 32;   // 0..31 local col
            int r0 = wr + m * 16 + lg * 4;
            *(f32x4*)&T[c * 132 + r0] = acc[m][nn];
          }
      }
      __syncthreads();
      #pragma unroll
      for (int it = 0; it < 4; ++it) {
        int idx = t + it * 256;                     // 32 rows x 32 f4
        int rr = idx >> 5, c4 = idx & 31;
        f32x4 v = *(const f32x4*)&T[rr * 132 + c4 * 4];
        *(f32x4*)&out[(size_t)(bj * 128 + p * 32 + rr) * N + bi * 128 + c4 * 4] = v;
      }
      __syncthreads();
    }
  }

  // direct tile (bi,bj) from registers
  #pragma unroll
  for (int m = 0; m < 4; ++m) {
    size_t gr0 = (size_t)(bi * 128 + wr + m * 16 + lg * 4);
    #pragma unroll
    for (int nn = 0; nn < 4; ++nn) {
      int gc = bj * 128 + wc + nn * 16 + lr;
      #pragma unroll
      for (int r = 0; r < 4; ++r)
        out[(gr0 + r) * N + gc] = acc[m][nn][r];
    }
  }
}

extern "C" void kernel_launch(void* const* d_in, const int* in_sizes, int n_in,
                              void* d_out, int out_size, void* d_ws, size_t ws_size,
                              hipStream_t stream) {
  const float* x    = (const float*)d_in[0];
  const int*   src  = (const int*)d_in[1];
  const int*   dst  = (const int*)d_in[2];
  const float* fcw  = (const float*)d_in[3];
  const float* fcb  = (const float*)d_in[4];
  const float* w1   = (const float*)d_in[5];
  const float* b1   = (const float*)d_in[6];
  const float* w2   = (const float*)d_in[7];
  const float* b2   = (const float*)d_in[8];
  const float* eps  = (const float*)d_in[9];
  const float* gamma= (const float*)d_in[10];
  const float* beta = (const float*)d_in[11];
  int n = in_sizes[0] / HID;   // 16000
  int e = in_sizes[1];         // 512000
  float* out = (float*)d_out;

  char* ws = (char*)d_ws;
  size_t off = 0;
  float* agg   = (float*)(ws + off); off += (size_t)n * HID * 4;                  // 8 MB
  float* h     = (float*)(ws + off); off += (size_t)n * OUT * 4;                  // 4 MB
  float* aggy  = (float*)(ws + off); off += (size_t)n * OUT * 4;                  // 4 MB
  unsigned short* xbf = (unsigned short*)(ws + off); off += (size_t)n * HID * 2;  // 4 MB
  unsigned short* hbf = (unsigned short*)(ws + off); off += (size_t)n * OUT * 2;  // 2 MB
  unsigned short* y2  = (unsigned short*)(ws + off); off += (size_t)n * OUT * 2;  // 2 MB
  float* stats = (float*)(ws + off); off += 512;
  int* cnt     = (int*)(ws + off); off += (size_t)n * 4;
  int* offsets = (int*)(ws + off); off += (size_t)(n + 1) * 4;
  int* cursor  = (int*)(ws + off); off += (size_t)n * 4;
  unsigned short* sorted_src = (unsigned short*)(ws + off); off += (size_t)e * 2;

  hipMemsetAsync(cnt, 0, (size_t)n * 4, stream);

  // xbf = bf16(x); cnt = histogram(dst)
  prep_k<<<2048, 256, 0, stream>>>(x, xbf, dst, cnt, n, e);
  // exclusive scan; zero stats
  scan_k<<<1, 1024, 0, stream>>>(cnt, offsets, cursor, stats, n);
  // sorted_src (ushort)
  place_k<<<512, 256, 0, stream>>>(src, dst, cursor, sorted_src, e);

  // agg = A @ x   (bf16 gather, fp32 accumulate; one wave per node)
  aggx_k<<<(n * 64 + 255) / 256, 256, 0, stream>>>(xbf, sorted_src, offsets, agg, n);
  // y2 = bf16(relu(agg @ w1^T + b1) @ w2^T)
  mlp_fused_k<<<n / 16, 256, 0, stream>>>(agg, w1, b1, w2, y2, n);
  // aggy = A @ y2  (one wave per node)
  agg2y_k<<<(n * 64 + 255) / 256, 256, 0, stream>>>(y2, sorted_src, offsets, aggy, n);
  // h = (1-eps)*h1 + eps*(aggy + b2); hbf; BN stats
  combine_k<<<n / 32, 256, 0, stream>>>(x, aggy, fcw, fcb, b2, eps, h, hbf, stats, n);
  hn_k<<<1024, 256, 0, stream>>>(h, stats, gamma, beta, out + (size_t)n * n, n);

  int nb = n >> 7;
  int nwg = nb * (nb + 1) / 2;
  gemm_k<<<nwg, 256, 0, stream>>>(hbf, xbf, out, n, nwg);
}

// Round 12
// 372.564 us; speedup vs baseline: 1.3789x; 1.0583x over previous
//
#include <hip/hip_runtime.h>
#include <hip/hip_bf16.h>

typedef __bf16 bf16x8 __attribute__((ext_vector_type(8)));
typedef float  f32x4  __attribute__((ext_vector_type(4)));
typedef unsigned short u16x8 __attribute__((ext_vector_type(8)));

#define HID 128
#define OUT 64
#define BN_EPS 1e-5f

__device__ __forceinline__ float bf2f(unsigned short u) {
  union { unsigned int i; float f; } c; c.i = ((unsigned)u) << 16; return c.f;
}

// ---------------- prep: xbf = bf16(x) AND histogram of dst ----------------
__global__ __launch_bounds__(256) void prep_k(
    const float* __restrict__ x, unsigned short* __restrict__ xbf,
    const int* __restrict__ dst, int* __restrict__ cnt, int n, int e)
{
  int gid = blockIdx.x * blockDim.x + threadIdx.x;
  int stride = gridDim.x * blockDim.x;
  int total = n * 32;               // f32x4 granules
  for (int idx = gid; idx < total; idx += stride) {
    f32x4 v = ((const f32x4*)x)[idx];
    ushort4 o;
    __bf16 b0 = (__bf16)v[0], b1 = (__bf16)v[1], b2 = (__bf16)v[2], b3 = (__bf16)v[3];
    o.x = *(unsigned short*)&b0; o.y = *(unsigned short*)&b1;
    o.z = *(unsigned short*)&b2; o.w = *(unsigned short*)&b3;
    ((ushort4*)xbf)[idx] = o;
  }
  for (int i = gid; i < e; i += stride)
    atomicAdd(&cnt[dst[i]], 1);
}

// ---------------- single-block exclusive scan (1024 thr); zero stats ----------------
__global__ __launch_bounds__(1024) void scan_k(
    const int* __restrict__ cnt, int* __restrict__ offsets,
    int* __restrict__ cursor, float* __restrict__ stats, int n)
{
  int t = threadIdx.x;
  if (t < 128) stats[t] = 0.f;
  __shared__ int part[1024];
  int chunk = (n + 1023) / 1024;
  int base = t * chunk;
  int s = 0;
  for (int i = 0; i < chunk; ++i) {
    int idx = base + i;
    if (idx < n) s += cnt[idx];
  }
  part[t] = s;
  __syncthreads();
  for (int off = 1; off < 1024; off <<= 1) {
    int v = 0;
    if (t >= off) v = part[t - off];
    __syncthreads();
    if (t >= off) part[t] += v;
    __syncthreads();
  }
  int run = (t == 0) ? 0 : part[t - 1];
  for (int i = 0; i < chunk; ++i) {
    int idx = base + i;
    if (idx < n) {
      offsets[idx] = run;
      cursor[idx]  = run;
      run += cnt[idx];
    }
  }
  if (t == 1023) offsets[n] = run;
}

// ---------------- place src ids (ushort) into dst-sorted order ----------------
__global__ __launch_bounds__(256) void place_k(
    const int* __restrict__ src, const int* __restrict__ dst,
    int* __restrict__ cursor, unsigned short* __restrict__ sorted_src, int e)
{
  int stride = gridDim.x * blockDim.x;
  for (int i = blockIdx.x * blockDim.x + threadIdx.x; i < e; i += stride) {
    int pos = atomicAdd(&cursor[dst[i]], 1);
    sorted_src[pos] = (unsigned short)src[i];
  }
}

// ---- agg[d] = segment sum of bf16 xbf (N x 128); one wave per d; 12 edges in flight ----
__global__ __launch_bounds__(256) void aggx_k(
    const unsigned short* __restrict__ xbf, const unsigned short* __restrict__ sorted_src,
    const int* __restrict__ offsets, float* __restrict__ agg, int n)
{
  int wave = (blockIdx.x * 256 + threadIdx.x) >> 6;
  int lane = threadIdx.x & 63;
  if (wave >= n) return;
  int qtr = lane >> 4;              // 4 quarter-waves: one edge each
  int l16 = lane & 15;              // 16 lanes x 8 bf16 = one 128-col row
  int beg = offsets[wave], end = offsets[wave + 1];
  float a0[8] = {}, a1[8] = {}, a2[8] = {};
  int i = beg + qtr;
  for (; i + 8 < end; i += 12) {
    int s0 = sorted_src[i];
    int s1 = sorted_src[i + 4];
    int s2 = sorted_src[i + 8];
    u16x8 v0 = *(const u16x8*)(xbf + (size_t)s0 * HID + l16 * 8);
    u16x8 v1 = *(const u16x8*)(xbf + (size_t)s1 * HID + l16 * 8);
    u16x8 v2 = *(const u16x8*)(xbf + (size_t)s2 * HID + l16 * 8);
    #pragma unroll
    for (int j = 0; j < 8; ++j) { a0[j] += bf2f(v0[j]); a1[j] += bf2f(v1[j]); a2[j] += bf2f(v2[j]); }
  }
  for (; i < end; i += 4) {
    int s0 = sorted_src[i];
    u16x8 v0 = *(const u16x8*)(xbf + (size_t)s0 * HID + l16 * 8);
    #pragma unroll
    for (int j = 0; j < 8; ++j) a0[j] += bf2f(v0[j]);
  }
  #pragma unroll
  for (int j = 0; j < 8; ++j) a0[j] += a1[j] + a2[j];
  #pragma unroll
  for (int j = 0; j < 8; ++j) a0[j] += __shfl_xor(a0[j], 16, 64);
  #pragma unroll
  for (int j = 0; j < 8; ++j) a0[j] += __shfl_xor(a0[j], 32, 64);
  if (qtr == 0) {
    f32x4 lo = {a0[0], a0[1], a0[2], a0[3]};
    f32x4 hi = {a0[4], a0[5], a0[6], a0[7]};
    *(f32x4*)(agg + (size_t)wave * HID + l16 * 8)     = lo;
    *(f32x4*)(agg + (size_t)wave * HID + l16 * 8 + 4) = hi;
  }
}

// ---- aggy[d] = segment sum of bf16 y2 (N x 64); one wave per d; 12 edges in flight ----
__global__ __launch_bounds__(256) void agg2y_k(
    const unsigned short* __restrict__ y2, const unsigned short* __restrict__ sorted_src,
    const int* __restrict__ offsets, float* __restrict__ aggy, int n)
{
  int wave = (blockIdx.x * 256 + threadIdx.x) >> 6;
  int lane = threadIdx.x & 63;
  if (wave >= n) return;
  int qtr = lane >> 4;
  int l16 = lane & 15;
  int beg = offsets[wave], end = offsets[wave + 1];
  f32x4 a0 = {0.f, 0.f, 0.f, 0.f}, a1 = {0.f, 0.f, 0.f, 0.f}, a2 = {0.f, 0.f, 0.f, 0.f};
  int i = beg + qtr;
  for (; i + 8 < end; i += 12) {
    int s0 = sorted_src[i];
    int s1 = sorted_src[i + 4];
    int s2 = sorted_src[i + 8];
    ushort4 v0 = *(const ushort4*)(y2 + (size_t)s0 * OUT + l16 * 4);
    ushort4 v1 = *(const ushort4*)(y2 + (size_t)s1 * OUT + l16 * 4);
    ushort4 v2 = *(const ushort4*)(y2 + (size_t)s2 * OUT + l16 * 4);
    a0[0] += bf2f(v0.x); a0[1] += bf2f(v0.y); a0[2] += bf2f(v0.z); a0[3] += bf2f(v0.w);
    a1[0] += bf2f(v1.x); a1[1] += bf2f(v1.y); a1[2] += bf2f(v1.z); a1[3] += bf2f(v1.w);
    a2[0] += bf2f(v2.x); a2[1] += bf2f(v2.y); a2[2] += bf2f(v2.z); a2[3] += bf2f(v2.w);
  }
  for (; i < end; i += 4) {
    int s0 = sorted_src[i];
    ushort4 v0 = *(const ushort4*)(y2 + (size_t)s0 * OUT + l16 * 4);
    a0[0] += bf2f(v0.x); a0[1] += bf2f(v0.y); a0[2] += bf2f(v0.z); a0[3] += bf2f(v0.w);
  }
  a0 += a1; a0 += a2;
  f32x4 other;
  #pragma unroll
  for (int j = 0; j < 4; ++j) other[j] = __shfl_xor(a0[j], 16, 64);
  a0 += other;
  #pragma unroll
  for (int j = 0; j < 4; ++j) other[j] = __shfl_xor(a0[j], 32, 64);
  a0 += other;
  if (qtr == 0)
    *(f32x4*)(aggy + (size_t)wave * OUT + l16 * 4) = a0;
}

// ---- y2 = bf16(relu(agg @ w1^T + b1) @ w2^T); h2a lives only in LDS ----
__global__ __launch_bounds__(256) void mlp_fused_k(
    const float* __restrict__ agg, const float* __restrict__ w1,
    const float* __restrict__ b1, const float* __restrict__ w2,
    unsigned short* __restrict__ y2, int n)
{
  __shared__ float aggs[16][132];
  __shared__ float h2s[16][132];
  int t = threadIdx.x;
  int rbase = blockIdx.x * 16;

  for (int idx = t; idx < 16 * 32; idx += 256) {
    int r = idx >> 5, c = idx & 31;
    ((f32x4*)&aggs[r][0])[c] = ((const f32x4*)(agg + (size_t)(rbase + r) * HID))[c];
  }
  __syncthreads();

  {
    int j = t & 127, rh = t >> 7;
    const f32x4* w1r = (const f32x4*)(w1 + (size_t)j * HID);
    float acc[8];
    float bj = b1[j];
    #pragma unroll
    for (int p = 0; p < 8; ++p) acc[p] = bj;
    for (int k = 0; k < 32; ++k) {
      f32x4 w = w1r[k];
      #pragma unroll
      for (int p = 0; p < 8; ++p) {
        f32x4 a = ((const f32x4*)&aggs[rh * 8 + p][0])[k];
        acc[p] += w[0] * a[0] + w[1] * a[1] + w[2] * a[2] + w[3] * a[3];
      }
    }
    #pragma unroll
    for (int p = 0; p < 8; ++p) h2s[rh * 8 + p][j] = fmaxf(acc[p], 0.f);
  }
  __syncthreads();

  {
    int o = t & 63, rq = t >> 6;
    const f32x4* w2r = (const f32x4*)(w2 + (size_t)o * HID);
    float acc[4] = {0.f, 0.f, 0.f, 0.f};
    for (int k = 0; k < 32; ++k) {
      f32x4 w = w2r[k];
      #pragma unroll
      for (int p = 0; p < 4; ++p) {
        f32x4 a = ((const f32x4*)&h2s[rq + p * 4][0])[k];
        acc[p] += w[0] * a[0] + w[1] * a[1] + w[2] * a[2] + w[3] * a[3];
      }
    }
    #pragma unroll
    for (int p = 0; p < 4; ++p) {
      __bf16 b = (__bf16)acc[p];
      y2[(size_t)(rbase + rq + p * 4) * OUT + o] = *(unsigned short*)&b;
    }
  }
}

// ---- h = (1-eps)*(x@fc_w^T+fc_b) + eps*(aggy + b2); hbf = bf16(h); BN stats ----
__global__ __launch_bounds__(256) void combine_k(
    const float* __restrict__ x, const float* __restrict__ aggy,
    const float* __restrict__ fcw, const float* __restrict__ fcb,
    const float* __restrict__ b2,
    const float* __restrict__ eps, float* __restrict__ h,
    unsigned short* __restrict__ hbf, float* __restrict__ stats, int n)
{
  __shared__ float xs[32][132];
  __shared__ float ls[256], lss[256];
  int t = threadIdx.x;
  int rbase = blockIdx.x * 32;

  for (int idx = t; idx < 32 * 32; idx += 256) {
    int r = idx >> 5, c = idx & 31;
    ((f32x4*)&xs[r][0])[c] = ((const f32x4*)(x + (size_t)(rbase + r) * HID))[c];
  }
  __syncthreads();

  int o = t & 63, rq = t >> 6;
  const f32x4* fwr = (const f32x4*)(fcw + (size_t)o * HID);
  float fb = fcb[o], bb = b2[o];
  float acc[8];
  #pragma unroll
  for (int p = 0; p < 8; ++p) acc[p] = fb;
  for (int k = 0; k < 32; ++k) {
    f32x4 w = fwr[k];
    #pragma unroll
    for (int p = 0; p < 8; ++p) {
      f32x4 a = ((const f32x4*)&xs[rq + p * 4][0])[k];
      acc[p] += w[0] * a[0] + w[1] * a[1] + w[2] * a[2] + w[3] * a[3];
    }
  }
  float s = 0.f, ss = 0.f;
  #pragma unroll
  for (int p = 0; p < 8; ++p) {
    int row = rbase + rq + p * 4;
    float a2 = aggy[(size_t)row * OUT + o] + bb;
    float ev = eps[row];
    float hv = (1.f - ev) * acc[p] + ev * a2;
    h[(size_t)row * OUT + o] = hv;
    __bf16 hb = (__bf16)hv;
    hbf[(size_t)row * OUT + o] = *(unsigned short*)&hb;
    s += hv; ss += hv * hv;
  }
  ls[t] = s; lss[t] = ss;
  __syncthreads();
  if (t < 64) {
    s  = ls[t]  + ls[t + 64]  + ls[t + 128]  + ls[t + 192];
    ss = lss[t] + lss[t + 64] + lss[t + 128] + lss[t + 192];
    atomicAdd(&stats[t], s);
    atomicAdd(&stats[64 + t], ss);
  }
}

// ---------------- hn = (h - mean) * rsqrt(var+eps) * gamma + beta ----------------
__global__ __launch_bounds__(256) void hn_k(
    const float* __restrict__ h, const float* __restrict__ stats,
    const float* __restrict__ gamma, const float* __restrict__ beta,
    float* __restrict__ outp, int n)
{
  int stride = gridDim.x * blockDim.x;
  int total  = n * OUT;
  float inv_n = 1.f / (float)n;
  for (int idx = blockIdx.x * blockDim.x + threadIdx.x; idx < total; idx += stride) {
    int col = idx & 63;
    float mean = stats[col] * inv_n;
    float var  = stats[64 + col] * inv_n - mean * mean;
    float sc   = rsqrtf(var + BN_EPS) * gamma[col];
    outp[idx] = (h[idx] - mean) * sc + beta[col];
  }
}

// ---- ret = 0.5 * [hbf|xbf] @ [hbf|xbf]^T, symmetric (bi<=bj);
//      all output stores assembled to full 128-col rows in LDS, nontemporal ----
__global__ __launch_bounds__(256, 4) void gemm_k(
    const unsigned short* __restrict__ hbf, const unsigned short* __restrict__ xbf,
    float* __restrict__ out, int n, int nwg)
{
  __shared__ char pool[32768];                 // exactly 32 KB
  __bf16* As = (__bf16*)pool;                  // 16 KB
  __bf16* Bs = (__bf16*)(pool + 16384);        // 16 KB
  float*  T  = (float*)pool;                   // 32x132 f32 = 16.9 KB (aliased)

  int nb = n >> 7;                  // 125
  int orig = blockIdx.x;
  int q = nwg >> 3, r = nwg & 7;
  int xcd = orig & 7, idx8 = orig >> 3;
  int bid = (xcd < r ? xcd * (q + 1) : r * (q + 1) + (xcd - r) * q) + idx8;

  int bi = 0, rem = bid;
  while (rem >= nb - bi) { rem -= nb - bi; ++bi; }
  int bj = bi + rem;
  int t = threadIdx.x;
  int w = t >> 6, lane = t & 63;
  int wr = (w >> 1) << 6;
  int wc = (w & 1) << 6;
  int lr = lane & 15, lg = lane >> 4;

  const uint4* ha = (const uint4*)(hbf + (size_t)bi * 128 * OUT);
  const uint4* hb = (const uint4*)(hbf + (size_t)bj * 128 * OUT);
  const uint4* xa = (const uint4*)(xbf + (size_t)bi * 128 * HID);
  const uint4* xb = (const uint4*)(xbf + (size_t)bj * 128 * HID);
  uint4* Asv = (uint4*)As;
  uint4* Bsv = (uint4*)Bs;

  f32x4 acc[4][4] = {};
  #pragma unroll
  for (int kc = 0; kc < 3; ++kc) {  // K = 192: kc0 <- hbf, kc1/2 <- xbf
    #pragma unroll
    for (int it = 0; it < 4; ++it) {
      int ch = t + it * 256;
      int row = ch >> 3, c = ch & 7;
      int sw = row * 8 + (c ^ (row & 7));
      uint4 va, vb;
      if (kc == 0) { va = ha[row * 8 + c];                  vb = hb[row * 8 + c]; }
      else         { va = xa[row * 16 + (kc - 1) * 8 + c];  vb = xb[row * 16 + (kc - 1) * 8 + c]; }
      Asv[sw] = va;
      Bsv[sw] = vb;
    }
    __syncthreads();
    const bf16x8* Ac = (const bf16x8*)As;
    const bf16x8* Bc = (const bf16x8*)Bs;
    #pragma unroll
    for (int ks = 0; ks < 2; ++ks) {
      bf16x8 a[4], b[4];
      #pragma unroll
      for (int m = 0; m < 4; ++m) {
        int ar = wr + m * 16 + lr;
        int br = wc + m * 16 + lr;
        a[m] = Ac[ar * 8 + ((ks * 4 + lg) ^ (ar & 7))];
        b[m] = Bc[br * 8 + ((ks * 4 + lg) ^ (br & 7))];
      }
      #pragma unroll
      for (int m = 0; m < 4; ++m)
        #pragma unroll
        for (int nn = 0; nn < 4; ++nn)
          acc[m][nn] = __builtin_amdgcn_mfma_f32_16x16x32_bf16(a[m], b[nn], acc[m][nn], 0, 0, 0);
    }
    __syncthreads();
  }

  #pragma unroll
  for (int m = 0; m < 4; ++m)
    #pragma unroll
    for (int nn = 0; nn < 4; ++nn)
      acc[m][nn] = acc[m][nn] * 0.5f;

  size_t N = (size_t)n;

  // mirrored tile (bj,bi): 4 passes of 32 columns; full-row nt stores
  if (bi != bj) {
    #pragma unroll
    for (int p = 0; p < 4; ++p) {
      if ((wc >> 6) == (p >> 1)) {
        int nn0 = (p & 1) * 2;
        #pragma unroll
        for (int m = 0; m < 4; ++m)
          #pragma unroll
          for (int nn = nn0; nn < nn0 + 2; ++nn) {
            int c  = nn * 16 + lr - (p & 1) * 32;   // 0..31 local col
            int r0 = wr + m * 16 + lg * 4;
            *(f32x4*)&T[c * 132 + r0] = acc[m][nn];
          }
      }
      __syncthreads();
      #pragma unroll
      for (int it = 0; it < 4; ++it) {
        int idx = t + it * 256;                     // 32 rows x 32 f4
        int rr = idx >> 5, c4 = idx & 31;
        f32x4 v = *(const f32x4*)&T[rr * 132 + c4 * 4];
        __builtin_nontemporal_store(v,
          (f32x4*)&out[(size_t)(bj * 128 + p * 32 + rr) * N + bi * 128 + c4 * 4]);
      }
      __syncthreads();
    }
  }

  // direct tile (bi,bj): 4 passes of 32 rows through LDS; full-row nt stores
  #pragma unroll
  for (int p = 0; p < 4; ++p) {
    if ((wr >> 6) == (p >> 1)) {                    // waves holding these rows
      int m0 = (p & 1) * 2;
      #pragma unroll
      for (int m = m0; m < m0 + 2; ++m)
        #pragma unroll
        for (int nn = 0; nn < 4; ++nn)
          #pragma unroll
          for (int rr2 = 0; rr2 < 4; ++rr2) {
            int rloc = (m - m0) * 16 + lg * 4 + rr2;  // 0..31 local row
            T[rloc * 132 + wc + nn * 16 + lr] = acc[m][nn][rr2];
          }
    }
    __syncthreads();
    #pragma unroll
    for (int it = 0; it < 4; ++it) {
      int idx = t + it * 256;                       // 32 rows x 32 f4
      int rr = idx >> 5, c4 = idx & 31;
      f32x4 v = *(const f32x4*)&T[rr * 132 + c4 * 4];
      __builtin_nontemporal_store(v,
        (f32x4*)&out[(size_t)(bi * 128 + p * 32 + rr) * N + bj * 128 + c4 * 4]);
    }
    __syncthreads();
  }
}

extern "C" void kernel_launch(void* const* d_in, const int* in_sizes, int n_in,
                              void* d_out, int out_size, void* d_ws, size_t ws_size,
                              hipStream_t stream) {
  const float* x    = (const float*)d_in[0];
  const int*   src  = (const int*)d_in[1];
  const int*   dst  = (const int*)d_in[2];
  const float* fcw  = (const float*)d_in[3];
  const float* fcb  = (const float*)d_in[4];
  const float* w1   = (const float*)d_in[5];
  const float* b1   = (const float*)d_in[6];
  const float* w2   = (const float*)d_in[7];
  const float* b2   = (const float*)d_in[8];
  const float* eps  = (const float*)d_in[9];
  const float* gamma= (const float*)d_in[10];
  const float* beta = (const float*)d_in[11];
  int n = in_sizes[0] / HID;   // 16000
  int e = in_sizes[1];         // 512000
  float* out = (float*)d_out;

  char* ws = (char*)d_ws;
  size_t off = 0;
  float* agg   = (float*)(ws + off); off += (size_t)n * HID * 4;                  // 8 MB
  float* h     = (float*)(ws + off); off += (size_t)n * OUT * 4;                  // 4 MB
  float* aggy  = (float*)(ws + off); off += (size_t)n * OUT * 4;                  // 4 MB
  unsigned short* xbf = (unsigned short*)(ws + off); off += (size_t)n * HID * 2;  // 4 MB
  unsigned short* hbf = (unsigned short*)(ws + off); off += (size_t)n * OUT * 2;  // 2 MB
  unsigned short* y2  = (unsigned short*)(ws + off); off += (size_t)n * OUT * 2;  // 2 MB
  float* stats = (float*)(ws + off); off += 512;
  int* cnt     = (int*)(ws + off); off += (size_t)n * 4;
  int* offsets = (int*)(ws + off); off += (size_t)(n + 1) * 4;
  int* cursor  = (int*)(ws + off); off += (size_t)n * 4;
  unsigned short* sorted_src = (unsigned short*)(ws + off); off += (size_t)e * 2;

  hipMemsetAsync(cnt, 0, (size_t)n * 4, stream);

  // xbf = bf16(x); cnt = histogram(dst)
  prep_k<<<2048, 256, 0, stream>>>(x, xbf, dst, cnt, n, e);
  // exclusive scan; zero stats
  scan_k<<<1, 1024, 0, stream>>>(cnt, offsets, cursor, stats, n);
  // sorted_src (ushort)
  place_k<<<512, 256, 0, stream>>>(src, dst, cursor, sorted_src, e);

  // agg = A @ x   (bf16 gather, fp32 accumulate; one wave per node)
  aggx_k<<<(n * 64 + 255) / 256, 256, 0, stream>>>(xbf, sorted_src, offsets, agg, n);
  // y2 = bf16(relu(agg @ w1^T + b1) @ w2^T)
  mlp_fused_k<<<n / 16, 256, 0, stream>>>(agg, w1, b1, w2, y2, n);
  // aggy = A @ y2  (one wave per node)
  agg2y_k<<<(n * 64 + 255) / 256, 256, 0, stream>>>(y2, sorted_src, offsets, aggy, n);
  // h = (1-eps)*h1 + eps*(aggy + b2); hbf; BN stats
  combine_k<<<n / 32, 256, 0, stream>>>(x, aggy, fcw, fcb, b2, eps, h, hbf, stats, n);
  hn_k<<<1024, 256, 0, stream>>>(h, stats, gamma, beta, out + (size_t)n * n, n);

  int nb = n >> 7;
  int nwg = nb * (nb + 1) / 2;
  gemm_k<<<nwg, 256, 0, stream>>>(hbf, xbf, out, n, nwg);
}

// Round 13
// 372.406 us; speedup vs baseline: 1.3795x; 1.0004x over previous
//
#include <hip/hip_runtime.h>
#include <hip/hip_bf16.h>

typedef __bf16 bf16x8 __attribute__((ext_vector_type(8)));
typedef float  f32x4  __attribute__((ext_vector_type(4)));
typedef unsigned short u16x8 __attribute__((ext_vector_type(8)));

#define HID 128
#define OUT 64
#define BN_EPS 1e-5f

__device__ __forceinline__ float bf2f(unsigned short u) {
  union { unsigned int i; float f; } c; c.i = ((unsigned)u) << 16; return c.f;
}

// ---------------- prep: xbf = bf16(x) AND histogram of dst ----------------
__global__ __launch_bounds__(256) void prep_k(
    const float* __restrict__ x, unsigned short* __restrict__ xbf,
    const int* __restrict__ dst, int* __restrict__ cnt, int n, int e)
{
  int gid = blockIdx.x * blockDim.x + threadIdx.x;
  int stride = gridDim.x * blockDim.x;
  int total = n * 32;               // f32x4 granules
  for (int idx = gid; idx < total; idx += stride) {
    f32x4 v = ((const f32x4*)x)[idx];
    ushort4 o;
    __bf16 b0 = (__bf16)v[0], b1 = (__bf16)v[1], b2 = (__bf16)v[2], b3 = (__bf16)v[3];
    o.x = *(unsigned short*)&b0; o.y = *(unsigned short*)&b1;
    o.z = *(unsigned short*)&b2; o.w = *(unsigned short*)&b3;
    ((ushort4*)xbf)[idx] = o;
  }
  for (int i = gid; i < e; i += stride)
    atomicAdd(&cnt[dst[i]], 1);
}

// ---------------- single-block exclusive scan (1024 thr); zero stats ----------------
__global__ __launch_bounds__(1024) void scan_k(
    const int* __restrict__ cnt, int* __restrict__ offsets,
    int* __restrict__ cursor, float* __restrict__ stats, int n)
{
  int t = threadIdx.x;
  if (t < 128) stats[t] = 0.f;
  __shared__ int part[1024];
  int chunk = (n + 1023) / 1024;
  int base = t * chunk;
  int s = 0;
  for (int i = 0; i < chunk; ++i) {
    int idx = base + i;
    if (idx < n) s += cnt[idx];
  }
  part[t] = s;
  __syncthreads();
  for (int off = 1; off < 1024; off <<= 1) {
    int v = 0;
    if (t >= off) v = part[t - off];
    __syncthreads();
    if (t >= off) part[t] += v;
    __syncthreads();
  }
  int run = (t == 0) ? 0 : part[t - 1];
  for (int i = 0; i < chunk; ++i) {
    int idx = base + i;
    if (idx < n) {
      offsets[idx] = run;
      cursor[idx]  = run;
      run += cnt[idx];
    }
  }
  if (t == 1023) offsets[n] = run;
}

// ---------------- place src ids (ushort) into dst-sorted order ----------------
__global__ __launch_bounds__(256) void place_k(
    const int* __restrict__ src, const int* __restrict__ dst,
    int* __restrict__ cursor, unsigned short* __restrict__ sorted_src, int e)
{
  int stride = gridDim.x * blockDim.x;
  for (int i = blockIdx.x * blockDim.x + threadIdx.x; i < e; i += stride) {
    int pos = atomicAdd(&cursor[dst[i]], 1);
    sorted_src[pos] = (unsigned short)src[i];
  }
}

// ---- agg[d] = segment sum of bf16 xbf (N x 128); one wave per d; 12 edges in flight ----
__global__ __launch_bounds__(256) void aggx_k(
    const unsigned short* __restrict__ xbf, const unsigned short* __restrict__ sorted_src,
    const int* __restrict__ offsets, float* __restrict__ agg, int n)
{
  int wave = (blockIdx.x * 256 + threadIdx.x) >> 6;
  int lane = threadIdx.x & 63;
  if (wave >= n) return;
  int qtr = lane >> 4;              // 4 quarter-waves: one edge each
  int l16 = lane & 15;              // 16 lanes x 8 bf16 = one 128-col row
  int beg = offsets[wave], end = offsets[wave + 1];
  float a0[8] = {}, a1[8] = {}, a2[8] = {};
  int i = beg + qtr;
  for (; i + 8 < end; i += 12) {
    int s0 = sorted_src[i];
    int s1 = sorted_src[i + 4];
    int s2 = sorted_src[i + 8];
    u16x8 v0 = *(const u16x8*)(xbf + (size_t)s0 * HID + l16 * 8);
    u16x8 v1 = *(const u16x8*)(xbf + (size_t)s1 * HID + l16 * 8);
    u16x8 v2 = *(const u16x8*)(xbf + (size_t)s2 * HID + l16 * 8);
    #pragma unroll
    for (int j = 0; j < 8; ++j) { a0[j] += bf2f(v0[j]); a1[j] += bf2f(v1[j]); a2[j] += bf2f(v2[j]); }
  }
  for (; i < end; i += 4) {
    int s0 = sorted_src[i];
    u16x8 v0 = *(const u16x8*)(xbf + (size_t)s0 * HID + l16 * 8);
    #pragma unroll
    for (int j = 0; j < 8; ++j) a0[j] += bf2f(v0[j]);
  }
  #pragma unroll
  for (int j = 0; j < 8; ++j) a0[j] += a1[j] + a2[j];
  #pragma unroll
  for (int j = 0; j < 8; ++j) a0[j] += __shfl_xor(a0[j], 16, 64);
  #pragma unroll
  for (int j = 0; j < 8; ++j) a0[j] += __shfl_xor(a0[j], 32, 64);
  if (qtr == 0) {
    f32x4 lo = {a0[0], a0[1], a0[2], a0[3]};
    f32x4 hi = {a0[4], a0[5], a0[6], a0[7]};
    *(f32x4*)(agg + (size_t)wave * HID + l16 * 8)     = lo;
    *(f32x4*)(agg + (size_t)wave * HID + l16 * 8 + 4) = hi;
  }
}

// ---- aggy[d] = segment sum of bf16 y2 (N x 64); one wave per d; 12 edges in flight ----
__global__ __launch_bounds__(256) void agg2y_k(
    const unsigned short* __restrict__ y2, const unsigned short* __restrict__ sorted_src,
    const int* __restrict__ offsets, float* __restrict__ aggy, int n)
{
  int wave = (blockIdx.x * 256 + threadIdx.x) >> 6;
  int lane = threadIdx.x & 63;
  if (wave >= n) return;
  int qtr = lane >> 4;
  int l16 = lane & 15;
  int beg = offsets[wave], end = offsets[wave + 1];
  f32x4 a0 = {0.f, 0.f, 0.f, 0.f}, a1 = {0.f, 0.f, 0.f, 0.f}, a2 = {0.f, 0.f, 0.f, 0.f};
  int i = beg + qtr;
  for (; i + 8 < end; i += 12) {
    int s0 = sorted_src[i];
    int s1 = sorted_src[i + 4];
    int s2 = sorted_src[i + 8];
    ushort4 v0 = *(const ushort4*)(y2 + (size_t)s0 * OUT + l16 * 4);
    ushort4 v1 = *(const ushort4*)(y2 + (size_t)s1 * OUT + l16 * 4);
    ushort4 v2 = *(const ushort4*)(y2 + (size_t)s2 * OUT + l16 * 4);
    a0[0] += bf2f(v0.x); a0[1] += bf2f(v0.y); a0[2] += bf2f(v0.z); a0[3] += bf2f(v0.w);
    a1[0] += bf2f(v1.x); a1[1] += bf2f(v1.y); a1[2] += bf2f(v1.z); a1[3] += bf2f(v1.w);
    a2[0] += bf2f(v2.x); a2[1] += bf2f(v2.y); a2[2] += bf2f(v2.z); a2[3] += bf2f(v2.w);
  }
  for (; i < end; i += 4) {
    int s0 = sorted_src[i];
    ushort4 v0 = *(const ushort4*)(y2 + (size_t)s0 * OUT + l16 * 4);
    a0[0] += bf2f(v0.x); a0[1] += bf2f(v0.y); a0[2] += bf2f(v0.z); a0[3] += bf2f(v0.w);
  }
  a0 += a1; a0 += a2;
  f32x4 other;
  #pragma unroll
  for (int j = 0; j < 4; ++j) other[j] = __shfl_xor(a0[j], 16, 64);
  a0 += other;
  #pragma unroll
  for (int j = 0; j < 4; ++j) other[j] = __shfl_xor(a0[j], 32, 64);
  a0 += other;
  if (qtr == 0)
    *(f32x4*)(aggy + (size_t)wave * OUT + l16 * 4) = a0;
}

// ---- y2 = bf16(relu(agg @ w1^T + b1) @ w2^T); h2a lives only in LDS ----
__global__ __launch_bounds__(256) void mlp_fused_k(
    const float* __restrict__ agg, const float* __restrict__ w1,
    const float* __restrict__ b1, const float* __restrict__ w2,
    unsigned short* __restrict__ y2, int n)
{
  __shared__ float aggs[16][132];
  __shared__ float h2s[16][132];
  int t = threadIdx.x;
  int rbase = blockIdx.x * 16;

  for (int idx = t; idx < 16 * 32; idx += 256) {
    int r = idx >> 5, c = idx & 31;
    ((f32x4*)&aggs[r][0])[c] = ((const f32x4*)(agg + (size_t)(rbase + r) * HID))[c];
  }
  __syncthreads();

  {
    int j = t & 127, rh = t >> 7;
    const f32x4* w1r = (const f32x4*)(w1 + (size_t)j * HID);
    float acc[8];
    float bj = b1[j];
    #pragma unroll
    for (int p = 0; p < 8; ++p) acc[p] = bj;
    for (int k = 0; k < 32; ++k) {
      f32x4 w = w1r[k];
      #pragma unroll
      for (int p = 0; p < 8; ++p) {
        f32x4 a = ((const f32x4*)&aggs[rh * 8 + p][0])[k];
        acc[p] += w[0] * a[0] + w[1] * a[1] + w[2] * a[2] + w[3] * a[3];
      }
    }
    #pragma unroll
    for (int p = 0; p < 8; ++p) h2s[rh * 8 + p][j] = fmaxf(acc[p], 0.f);
  }
  __syncthreads();

  {
    int o = t & 63, rq = t >> 6;
    const f32x4* w2r = (const f32x4*)(w2 + (size_t)o * HID);
    float acc[4] = {0.f, 0.f, 0.f, 0.f};
    for (int k = 0; k < 32; ++k) {
      f32x4 w = w2r[k];
      #pragma unroll
      for (int p = 0; p < 4; ++p) {
        f32x4 a = ((const f32x4*)&h2s[rq + p * 4][0])[k];
        acc[p] += w[0] * a[0] + w[1] * a[1] + w[2] * a[2] + w[3] * a[3];
      }
    }
    #pragma unroll
    for (int p = 0; p < 4; ++p) {
      __bf16 b = (__bf16)acc[p];
      y2[(size_t)(rbase + rq + p * 4) * OUT + o] = *(unsigned short*)&b;
    }
  }
}

// ---- h = (1-eps)*(x@fc_w^T+fc_b) + eps*(aggy + b2); hbf = bf16(h); BN stats ----
__global__ __launch_bounds__(256) void combine_k(
    const float* __restrict__ x, const float* __restrict__ aggy,
    const float* __restrict__ fcw, const float* __restrict__ fcb,
    const float* __restrict__ b2,
    const float* __restrict__ eps, float* __restrict__ h,
    unsigned short* __restrict__ hbf, float* __restrict__ stats, int n)
{
  __shared__ float xs[32][132];
  __shared__ float ls[256], lss[256];
  int t = threadIdx.x;
  int rbase = blockIdx.x * 32;

  for (int idx = t; idx < 32 * 32; idx += 256) {
    int r = idx >> 5, c = idx & 31;
    ((f32x4*)&xs[r][0])[c] = ((const f32x4*)(x + (size_t)(rbase + r) * HID))[c];
  }
  __syncthreads();

  int o = t & 63, rq = t >> 6;
  const f32x4* fwr = (const f32x4*)(fcw + (size_t)o * HID);
  float fb = fcb[o], bb = b2[o];
  float acc[8];
  #pragma unroll
  for (int p = 0; p < 8; ++p) acc[p] = fb;
  for (int k = 0; k < 32; ++k) {
    f32x4 w = fwr[k];
    #pragma unroll
    for (int p = 0; p < 8; ++p) {
      f32x4 a = ((const f32x4*)&xs[rq + p * 4][0])[k];
      acc[p] += w[0] * a[0] + w[1] * a[1] + w[2] * a[2] + w[3] * a[3];
    }
  }
  float s = 0.f, ss = 0.f;
  #pragma unroll
  for (int p = 0; p < 8; ++p) {
    int row = rbase + rq + p * 4;
    float a2 = aggy[(size_t)row * OUT + o] + bb;
    float ev = eps[row];
    float hv = (1.f - ev) * acc[p] + ev * a2;
    h[(size_t)row * OUT + o] = hv;
    __bf16 hb = (__bf16)hv;
    hbf[(size_t)row * OUT + o] = *(unsigned short*)&hb;
    s += hv; ss += hv * hv;
  }
  ls[t] = s; lss[t] = ss;
  __syncthreads();
  if (t < 64) {
    s  = ls[t]  + ls[t + 64]  + ls[t + 128]  + ls[t + 192];
    ss = lss[t] + lss[t + 64] + lss[t + 128] + lss[t + 192];
    atomicAdd(&stats[t], s);
    atomicAdd(&stats[64 + t], ss);
  }
}

// ---- ret = 0.5 * [hbf|xbf] @ [hbf|xbf]^T, symmetric (bi<=bj), full-row nt stores;
//      blocks with orig >= nwg run the BN-normalize (hn) tail concurrently ----
__global__ __launch_bounds__(256, 4) void gemm_k(
    const unsigned short* __restrict__ hbf, const unsigned short* __restrict__ xbf,
    const float* __restrict__ h, const float* __restrict__ stats,
    const float* __restrict__ gamma, const float* __restrict__ beta,
    float* __restrict__ out, float* __restrict__ outhn, int n, int nwg, int nhb)
{
  __shared__ char pool[32768];                 // exactly 32 KB
  __bf16* As = (__bf16*)pool;                  // 16 KB
  __bf16* Bs = (__bf16*)(pool + 16384);        // 16 KB
  float*  T  = (float*)pool;                   // 32x132 f32 = 16.9 KB (aliased)

  int orig = blockIdx.x;

  // ----- fused hn tail blocks -----
  if (orig >= nwg) {
    int hb = orig - nwg;
    int stride = nhb * 256;
    int total4 = n * OUT / 4;                  // f32x4 granules
    float inv_n = 1.f / (float)n;
    for (int idx = hb * 256 + threadIdx.x; idx < total4; idx += stride) {
      int c4 = (idx & 15) * 4;                 // column of first lane elem
      f32x4 hv = ((const f32x4*)h)[idx];
      f32x4 o;
      #pragma unroll
      for (int j = 0; j < 4; ++j) {
        int col = c4 + j;
        float mean = stats[col] * inv_n;
        float var  = stats[64 + col] * inv_n - mean * mean;
        float sc   = rsqrtf(var + BN_EPS) * gamma[col];
        o[j] = (hv[j] - mean) * sc + beta[col];
      }
      __builtin_nontemporal_store(o, (f32x4*)&outhn[(size_t)idx * 4]);
    }
    return;
  }

  int nb = n >> 7;                  // 125
  int q = nwg >> 3, r = nwg & 7;
  int xcd = orig & 7, idx8 = orig >> 3;
  int bid = (xcd < r ? xcd * (q + 1) : r * (q + 1) + (xcd - r) * q) + idx8;

  int bi = 0, rem = bid;
  while (rem >= nb - bi) { rem -= nb - bi; ++bi; }
  int bj = bi + rem;
  int t = threadIdx.x;
  int w = t >> 6, lane = t & 63;
  int wr = (w >> 1) << 6;
  int wc = (w & 1) << 6;
  int lr = lane & 15, lg = lane >> 4;

  const uint4* ha = (const uint4*)(hbf + (size_t)bi * 128 * OUT);
  const uint4* hb_ = (const uint4*)(hbf + (size_t)bj * 128 * OUT);
  const uint4* xa = (const uint4*)(xbf + (size_t)bi * 128 * HID);
  const uint4* xb = (const uint4*)(xbf + (size_t)bj * 128 * HID);
  uint4* Asv = (uint4*)As;
  uint4* Bsv = (uint4*)Bs;

  f32x4 acc[4][4] = {};
  #pragma unroll
  for (int kc = 0; kc < 3; ++kc) {  // K = 192: kc0 <- hbf, kc1/2 <- xbf
    #pragma unroll
    for (int it = 0; it < 4; ++it) {
      int ch = t + it * 256;
      int row = ch >> 3, c = ch & 7;
      int sw = row * 8 + (c ^ (row & 7));
      uint4 va, vb;
      if (kc == 0) { va = ha[row * 8 + c];                  vb = hb_[row * 8 + c]; }
      else         { va = xa[row * 16 + (kc - 1) * 8 + c];  vb = xb[row * 16 + (kc - 1) * 8 + c]; }
      Asv[sw] = va;
      Bsv[sw] = vb;
    }
    __syncthreads();
    const bf16x8* Ac = (const bf16x8*)As;
    const bf16x8* Bc = (const bf16x8*)Bs;
    #pragma unroll
    for (int ks = 0; ks < 2; ++ks) {
      bf16x8 a[4], b[4];
      #pragma unroll
      for (int m = 0; m < 4; ++m) {
        int ar = wr + m * 16 + lr;
        int br = wc + m * 16 + lr;
        a[m] = Ac[ar * 8 + ((ks * 4 + lg) ^ (ar & 7))];
        b[m] = Bc[br * 8 + ((ks * 4 + lg) ^ (br & 7))];
      }
      #pragma unroll
      for (int m = 0; m < 4; ++m)
        #pragma unroll
        for (int nn = 0; nn < 4; ++nn)
          acc[m][nn] = __builtin_amdgcn_mfma_f32_16x16x32_bf16(a[m], b[nn], acc[m][nn], 0, 0, 0);
    }
    __syncthreads();
  }

  #pragma unroll
  for (int m = 0; m < 4; ++m)
    #pragma unroll
    for (int nn = 0; nn < 4; ++nn)
      acc[m][nn] = acc[m][nn] * 0.5f;

  size_t N = (size_t)n;

  // mirrored tile (bj,bi): 4 passes of 32 columns; full-row nt stores
  if (bi != bj) {
    #pragma unroll
    for (int p = 0; p < 4; ++p) {
      if ((wc >> 6) == (p >> 1)) {
        int nn0 = (p & 1) * 2;
        #pragma unroll
        for (int m = 0; m < 4; ++m)
          #pragma unroll
          for (int nn = nn0; nn < nn0 + 2; ++nn) {
            int c  = nn * 16 + lr - (p & 1) * 32;   // 0..31 local col
            int r0 = wr + m * 16 + lg * 4;
            *(f32x4*)&T[c * 132 + r0] = acc[m][nn];
          }
      }
      __syncthreads();
      #pragma unroll
      for (int it = 0; it < 4; ++it) {
        int idx = t + it * 256;                     // 32 rows x 32 f4
        int rr = idx >> 5, c4 = idx & 31;
        f32x4 v = *(const f32x4*)&T[rr * 132 + c4 * 4];
        __builtin_nontemporal_store(v,
          (f32x4*)&out[(size_t)(bj * 128 + p * 32 + rr) * N + bi * 128 + c4 * 4]);
      }
      __syncthreads();
    }
  }

  // direct tile (bi,bj): 4 passes of 32 rows through LDS; full-row nt stores
  #pragma unroll
  for (int p = 0; p < 4; ++p) {
    if ((wr >> 6) == (p >> 1)) {                    // waves holding these rows
      int m0 = (p & 1) * 2;
      #pragma unroll
      for (int m = m0; m < m0 + 2; ++m)
        #pragma unroll
        for (int nn = 0; nn < 4; ++nn)
          #pragma unroll
          for (int rr2 = 0; rr2 < 4; ++rr2) {
            int rloc = (m - m0) * 16 + lg * 4 + rr2;  // 0..31 local row
            T[rloc * 132 + wc + nn * 16 + lr] = acc[m][nn][rr2];
          }
    }
    __syncthreads();
    #pragma unroll
    for (int it = 0; it < 4; ++it) {
      int idx = t + it * 256;                       // 32 rows x 32 f4
      int rr = idx >> 5, c4 = idx & 31;
      f32x4 v = *(const f32x4*)&T[rr * 132 + c4 * 4];
      __builtin_nontemporal_store(v,
        (f32x4*)&out[(size_t)(bi * 128 + p * 32 + rr) * N + bj * 128 + c4 * 4]);
    }
    __syncthreads();
  }
}

extern "C" void kernel_launch(void* const* d_in, const int* in_sizes, int n_in,
                              void* d_out, int out_size, void* d_ws, size_t ws_size,
                              hipStream_t stream) {
  const float* x    = (const float*)d_in[0];
  const int*   src  = (const int*)d_in[1];
  const int*   dst  = (const int*)d_in[2];
  const float* fcw  = (const float*)d_in[3];
  const float* fcb  = (const float*)d_in[4];
  const float* w1   = (const float*)d_in[5];
  const float* b1   = (const float*)d_in[6];
  const float* w2   = (const float*)d_in[7];
  const float* b2   = (const float*)d_in[8];
  const float* eps  = (const float*)d_in[9];
  const float* gamma= (const float*)d_in[10];
  const float* beta = (const float*)d_in[11];
  int n = in_sizes[0] / HID;   // 16000
  int e = in_sizes[1];         // 512000
  float* out = (float*)d_out;

  char* ws = (char*)d_ws;
  size_t off = 0;
  float* agg   = (float*)(ws + off); off += (size_t)n * HID * 4;                  // 8 MB
  float* h     = (float*)(ws + off); off += (size_t)n * OUT * 4;                  // 4 MB
  float* aggy  = (float*)(ws + off); off += (size_t)n * OUT * 4;                  // 4 MB
  unsigned short* xbf = (unsigned short*)(ws + off); off += (size_t)n * HID * 2;  // 4 MB
  unsigned short* hbf = (unsigned short*)(ws + off); off += (size_t)n * OUT * 2;  // 2 MB
  unsigned short* y2  = (unsigned short*)(ws + off); off += (size_t)n * OUT * 2;  // 2 MB
  float* stats = (float*)(ws + off); off += 512;
  int* cnt     = (int*)(ws + off); off += (size_t)n * 4;
  int* offsets = (int*)(ws + off); off += (size_t)(n + 1) * 4;
  int* cursor  = (int*)(ws + off); off += (size_t)n * 4;
  unsigned short* sorted_src = (unsigned short*)(ws + off); off += (size_t)e * 2;

  hipMemsetAsync(cnt, 0, (size_t)n * 4, stream);

  // xbf = bf16(x); cnt = histogram(dst)
  prep_k<<<2048, 256, 0, stream>>>(x, xbf, dst, cnt, n, e);
  // exclusive scan; zero stats
  scan_k<<<1, 1024, 0, stream>>>(cnt, offsets, cursor, stats, n);
  // sorted_src (ushort)
  place_k<<<512, 256, 0, stream>>>(src, dst, cursor, sorted_src, e);

  // agg = A @ x   (bf16 gather, fp32 accumulate; one wave per node)
  aggx_k<<<(n * 64 + 255) / 256, 256, 0, stream>>>(xbf, sorted_src, offsets, agg, n);
  // y2 = bf16(relu(agg @ w1^T + b1) @ w2^T)
  mlp_fused_k<<<n / 16, 256, 0, stream>>>(agg, w1, b1, w2, y2, n);
  // aggy = A @ y2  (one wave per node)
  agg2y_k<<<(n * 64 + 255) / 256, 256, 0, stream>>>(y2, sorted_src, offsets, aggy, n);
  // h = (1-eps)*h1 + eps*(aggy + b2); hbf; BN stats
  combine_k<<<n / 32, 256, 0, stream>>>(x, aggy, fcw, fcb, b2, eps, h, hbf, stats, n);

  // ret GEMM + fused hn tail (128 extra blocks)
  int nb = n >> 7;
  int nwg = nb * (nb + 1) / 2;
  int nhb = 128;
  gemm_k<<<nwg + nhb, 256, 0, stream>>>(hbf, xbf, h, stats, gamma, beta,
                                        out, out + (size_t)n * n, n, nwg, nhb);
}